// Round 5
// baseline (1424.772 us; speedup 1.0000x reference)
//
#include <hip/hip_runtime.h>

// ---- problem constants ----
#define B_   2048
#define T_   512
#define H_   128
#define G_   512
#define R_   8      // batch rows per block
#define NTHR 512    // 8 waves: 0-3 layer0, 4-7 layer1+proj; each owns 32 units

typedef _Float16 f16;
typedef _Float16 f16x8 __attribute__((ext_vector_type(8)));
typedef float    f32x4 __attribute__((ext_vector_type(4)));
typedef int      i32x2 __attribute__((ext_vector_type(2)));

// ---- LDS layout (bytes). h tiles: row stride 256 B, XOR swizzle ((row&7)<<4) ----
#define OFF_W1    0                       // w_ih1 f16 [512][128] swizzled = 131072
#define OFF_RING  131072                  // h1 ring: 4 slots x [8][128] f16 = 8192
#define OFF_HB    139264                  // h2 state: 2 bufs x [8][128] f16 = 4096
#define OFF_XT    143360                  // x tiles: 2 bufs x 8 tok x 128 B = 2048
#define LDS_BYTES 145408

__device__ __forceinline__ float rcp_(float v) {
#if __has_builtin(__builtin_amdgcn_rcpf)
  return __builtin_amdgcn_rcpf(v);
#else
  return 1.0f / v;
#endif
}
__device__ __forceinline__ float sig_(float v)  { return rcp_(1.0f + __expf(-v)); }
__device__ __forceinline__ float tanh_(float v) { return 1.0f - 2.0f * rcp_(__expf(2.0f * v) + 1.0f); }

__device__ __forceinline__ f16x8 cvt8(const float* __restrict__ p) {
  float4 a = ((const float4*)p)[0];
  float4 b = ((const float4*)p)[1];
  f16x8 v;
  v[0]=(f16)a.x; v[1]=(f16)a.y; v[2]=(f16)a.z; v[3]=(f16)a.w;
  v[4]=(f16)b.x; v[5]=(f16)b.y; v[6]=(f16)b.z; v[7]=(f16)b.w;
  return v;
}
__device__ __forceinline__ f32x4 mfma16(f16x8 a, f16x8 b, f32x4 c) {
  return __builtin_amdgcn_mfma_f32_16x16x32_f16(a, b, c, 0, 0, 0);
}

// v_permlane32_swap: x = {a.lo, b.lo} (even-row spread), y = {a.hi, b.hi} (odd)
__device__ __forceinline__ void pls2_(float a, float b, float& x, float& y) {
#if __has_builtin(__builtin_amdgcn_permlane32_swap)
  i32x2 r = __builtin_amdgcn_permlane32_swap(__float_as_int(a), __float_as_int(b),
                                             false, false);
  x = __int_as_float(r.x); y = __int_as_float(r.y);
#else
  asm volatile("v_permlane32_swap_b32 %0, %1" : "+v"(a), "+v"(b));
  x = a; y = b;
#endif
}

__global__ __launch_bounds__(NTHR, 2)
void lstm_spec(const float* __restrict__ x,
               const float* __restrict__ w_ih0, const float* __restrict__ w_hh0,
               const float* __restrict__ b_ih0, const float* __restrict__ b_hh0,
               const float* __restrict__ w_ih1, const float* __restrict__ w_hh1,
               const float* __restrict__ b_ih1, const float* __restrict__ b_hh1,
               const float* __restrict__ fc_w,  const float* __restrict__ fc_b,
               float* __restrict__ out)
{
  extern __shared__ char lds[];
  char*  w1L   = lds + OFF_W1;
  char*  ringB = lds + OFF_RING;
  char*  hBB   = lds + OFF_HB;
  char*  xT    = lds + OFF_XT;

  const int tid  = (int)threadIdx.x;
  const int lane = tid & 63;
  const int wv   = tid >> 6;
  const int n    = lane & 15;
  const int hi   = lane >> 4;
  const int u032 = (wv & 3) * 32;
  const bool isP0 = (wv < 4);
  const int blk  = (int)blockIdx.x;
  const int rsw  = (n & 7) << 4;

  // ---- stage w_ih1 -> LDS f16, swizzled ----
  for (int idx = tid; idx < G_*16; idx += NTHR) {
    const int g = idx >> 4, s7 = idx & 15;
    f16x8 v = cvt8(w_ih1 + g*H_ + s7*8);
    *(f16x8*)(w1L + g*256 + ((s7*16) ^ ((g&7)<<4))) = v;
  }
  // zero ring + hB + xT (14336 B = 3584 dwords) -- xT pad bytes must be finite!
  for (int i = tid; i < 3584; i += NTHR) ((unsigned*)ringB)[i] = 0u;
  __syncthreads();

  // ---- wave 7: x prologue (chunk 0 -> xT buf0; chunk 1 -> regs) ----
  float xr0 = 0.f, xr1 = 0.f, xr2 = 0.f;
  if (wv == 7) {
    const int tok = lane >> 3, r = lane & 7;
    const size_t base = (size_t)(blk*R_ + r) * T_;
    const float a0 = x[(base + tok)*3+0];
    const float a1 = x[(base + tok)*3+1];
    const float a2 = x[(base + tok)*3+2];
    f16* w = (f16*)(xT + tok*128 + r*16);
    w[0] = (f16)a0; w[1] = (f16)a1; w[2] = (f16)a2;
    xr0 = x[(base + 8 + tok)*3+0];
    xr1 = x[(base + 8 + tok)*3+1];
    xr2 = x[(base + 8 + tok)*3+2];
  }

  // ---- role-resident weight fragments (128 VGPRs) ----
  f16x8 wrec[4][4][2];                 // whh0 (P0) or whh1 (P1)
  const float* wm = isP0 ? w_hh0 : w_hh1;
  #pragma unroll
  for (int q = 0; q < 4; ++q)
    #pragma unroll
    for (int kc = 0; kc < 4; ++kc)
      #pragma unroll
      for (int nt = 0; nt < 2; ++nt)
        wrec[q][kc][nt] = cvt8(wm + (q*H_ + u032 + nt*16 + n)*H_ + kc*32 + hi*8);

  f16x8 w0p[4][2];                     // P0 only: padded w_ih0 B-frags (K=32, k>=3 zero)
  float bias[4][2];
  #pragma unroll
  for (int q = 0; q < 4; ++q)
    #pragma unroll
    for (int nt = 0; nt < 2; ++nt) {
      const int g = q*H_ + u032 + nt*16 + n;
      if (isP0) {
        bias[q][nt] = b_ih0[g] + b_hh0[g];
        f16x8 z;
        #pragma unroll
        for (int e = 0; e < 8; ++e) z[e] = (f16)0.f;
        if (hi == 0) {
          z[0] = (f16)w_ih0[g*3+0];
          z[1] = (f16)w_ih0[g*3+1];
          z[2] = (f16)w_ih0[g*3+2];
        }
        w0p[q][nt] = z;
      } else {
        bias[q][nt] = b_ih1[g] + b_hh1[g];
        #pragma unroll
        for (int e = 0; e < 8; ++e) w0p[q][nt][e] = (f16)0.f;
      }
    }

  int offA[4];
  #pragma unroll
  for (int kc = 0; kc < 4; ++kc)
    offA[kc] = (n&7)*256 + ((kc*64 + hi*16) ^ rsw);

  float c0[2] = {0.f, 0.f}, c1[2] = {0.f, 0.f};
  f32x4 xpP[4][2];
  const int rowbase = (hi & 1)*4 + ((lane >= 32) ? 2 : 0);
  int colb[2];
  colb[0] = 2*(u032 + n); colb[1] = 2*(u032 + 16 + n);
  __syncthreads();

  for (int s = 0; s < T_ + 2; ++s) {
    // ---- x staging: wave 7, once per 8 steps (write c+1, load c+2) ----
    if (wv == 7 && (s & 7) == 3) {
      const int c = s >> 3;
      const int tok = lane >> 3, r = lane & 7;
      if (c <= 61) {   // issue loads early: latency hides under this step
        const size_t base = (size_t)(blk*R_ + r) * T_ + (8*(c+2) + tok);
        const float a0 = x[base*3+0], a1 = x[base*3+1], a2 = x[base*3+2];
        f16* w = (f16*)(xT + ((c+1)&1)*1024 + tok*128 + r*16);
        w[0] = (f16)xr0; w[1] = (f16)xr1; w[2] = (f16)xr2;
        xr0 = a0; xr1 = a1; xr2 = a2;
      } else if (c == 62) {
        f16* w = (f16*)(xT + ((c+1)&1)*1024 + tok*128 + r*16);
        w[0] = (f16)xr0; w[1] = (f16)xr1; w[2] = (f16)xr2;
      }
    }

    if (isP0) {
      // ================= layer 0 (token s) =================
      if (s < T_) {
        const char* pa = ringB + ((s-1)&3)*2048;
        const f16x8 ax = *(const f16x8*)(xT + ((s>>3)&1)*1024 + (s&7)*128 + (n&7)*16);
        f32x4 acc[4][2];
        #pragma unroll
        for (int q = 0; q < 4; ++q)
          #pragma unroll
          for (int nt = 0; nt < 2; ++nt) {
            f32x4 a; a[0]=bias[q][nt]; a[1]=bias[q][nt]; a[2]=bias[q][nt]; a[3]=bias[q][nt];
            acc[q][nt] = mfma16(ax, w0p[q][nt], a);
          }
        #pragma unroll
        for (int kc = 0; kc < 4; ++kc) {
          const f16x8 af = *(const f16x8*)(pa + offA[kc]);
          #pragma unroll
          for (int q = 0; q < 4; ++q)
            #pragma unroll
            for (int nt = 0; nt < 2; ++nt)
              acc[q][nt] = mfma16(af, wrec[q][kc][nt], acc[q][nt]);
        }
        char* wr = ringB + (s&3)*2048;
        #pragma unroll
        for (int nt = 0; nt < 2; ++nt) {
          float gA[4], gB[4], d0, d1;
          #pragma unroll
          for (int q = 0; q < 4; ++q) {
            pls2_(acc[q][nt][0], acc[q][nt][2], gA[q], d0);
            pls2_(acc[q][nt][1], acc[q][nt][3], gB[q], d1);
          }
          {
            const float iv = sig_(gA[0]), fv = sig_(gA[1]), gv = tanh_(gA[2]), ov = sig_(gA[3]);
            c0[nt] = fv*c0[nt] + iv*gv;
            const float h = ov * tanh_(c0[nt]);
            *(f16*)(wr + rowbase*256 + (colb[nt] ^ (rowbase<<4))) = (f16)h;
          }
          {
            const float iv = sig_(gB[0]), fv = sig_(gB[1]), gv = tanh_(gB[2]), ov = sig_(gB[3]);
            c1[nt] = fv*c1[nt] + iv*gv;
            const float h = ov * tanh_(c1[nt]);
            *(f16*)(wr + (rowbase+1)*256 + (colb[nt] ^ ((rowbase+1)<<4))) = (f16)h;
          }
        }
      }
    } else {
      // ================= proj (tokens s-2, s-1) every even step =================
      if ((s & 1) == 0 && s >= 2 && s <= T_) {
        const char* paE = ringB + ((s-2)&3)*2048;
        const char* paO = ringB + ((s-1)&3)*2048;
        const char* pa  = (n < 8) ? paE : paO;
        #pragma unroll
        for (int q = 0; q < 4; ++q)
          #pragma unroll
          for (int nt = 0; nt < 2; ++nt) {
            xpP[q][nt][0]=bias[q][nt]; xpP[q][nt][1]=bias[q][nt];
            xpP[q][nt][2]=bias[q][nt]; xpP[q][nt][3]=bias[q][nt];
          }
        #pragma unroll
        for (int kc = 0; kc < 4; ++kc) {
          const f16x8 a = *(const f16x8*)(pa + offA[kc]);
          #pragma unroll
          for (int q = 0; q < 4; ++q)
            #pragma unroll
            for (int nt = 0; nt < 2; ++nt) {
              const f16x8 bf = *(const f16x8*)(w1L + (q*H_ + u032 + nt*16 + n)*256
                                               + ((kc*64 + hi*16) ^ rsw));
              xpP[q][nt] = mfma16(a, bf, xpP[q][nt]);
            }
        }
      }
      // ================= layer 1 (token s-2) =================
      if (s >= 2) {
        const bool odd = (s & 1);
        const char* pb = hBB + (s&1)*2048;
        f32x4 acc[4][2];
        #pragma unroll
        for (int q = 0; q < 4; ++q)
          #pragma unroll
          for (int nt = 0; nt < 2; ++nt) acc[q][nt] = xpP[q][nt];
        #pragma unroll
        for (int kc = 0; kc < 4; ++kc) {
          const f16x8 af = *(const f16x8*)(pb + offA[kc]);
          #pragma unroll
          for (int q = 0; q < 4; ++q)
            #pragma unroll
            for (int nt = 0; nt < 2; ++nt)
              acc[q][nt] = mfma16(af, wrec[q][kc][nt], acc[q][nt]);
        }
        char* wr = hBB + ((s+1)&1)*2048;
        #pragma unroll
        for (int nt = 0; nt < 2; ++nt) {
          float gA[4], gB[4];
          #pragma unroll
          for (int q = 0; q < 4; ++q) {
            float ex, ey, fx, fy;
            pls2_(acc[q][nt][0], acc[q][nt][2], ex, ey);
            gA[q] = odd ? ey : ex;
            pls2_(acc[q][nt][1], acc[q][nt][3], fx, fy);
            gB[q] = odd ? fy : fx;
          }
          {
            const float iv = sig_(gA[0]), fv = sig_(gA[1]), gv = tanh_(gA[2]), ov = sig_(gA[3]);
            c0[nt] = fv*c0[nt] + iv*gv;
            const float h = ov * tanh_(c0[nt]);
            *(f16*)(wr + rowbase*256 + (colb[nt] ^ (rowbase<<4))) = (f16)h;
          }
          {
            const float iv = sig_(gB[0]), fv = sig_(gB[1]), gv = tanh_(gB[2]), ov = sig_(gB[3]);
            c1[nt] = fv*c1[nt] + iv*gv;
            const float h = ov * tanh_(c1[nt]);
            *(f16*)(wr + (rowbase+1)*256 + (colb[nt] ^ ((rowbase+1)<<4))) = (f16)h;
          }
        }
      }
    }
    __syncthreads();
  }

  // ---- FC head: final h2 is in hBB buf (T_+2)&1 == 0 ----
  if (tid < R_*2) {
    const int r = tid >> 1, o = tid & 1;
    float acc = fc_b[o];
    #pragma unroll 4
    for (int d = 0; d < H_; ++d) {
      const f16 hv = *(const f16*)(hBB + r*256 + ((2*d) ^ ((r&7)<<4)));
      acc += (float)hv * fc_w[o*H_ + d];
    }
    out[(blk*R_ + r)*2 + o] = acc;
  }
}

extern "C" void kernel_launch(void* const* d_in, const int* in_sizes, int n_in,
                              void* d_out, int out_size, void* d_ws, size_t ws_size,
                              hipStream_t stream) {
  const float* x     = (const float*)d_in[0];
  const float* w_ih0 = (const float*)d_in[1];
  const float* w_hh0 = (const float*)d_in[2];
  const float* b_ih0 = (const float*)d_in[3];
  const float* b_hh0 = (const float*)d_in[4];
  const float* w_ih1 = (const float*)d_in[5];
  const float* w_hh1 = (const float*)d_in[6];
  const float* b_ih1 = (const float*)d_in[7];
  const float* b_hh1 = (const float*)d_in[8];
  const float* fc_w  = (const float*)d_in[9];
  const float* fc_b  = (const float*)d_in[10];
  (void)in_sizes; (void)n_in; (void)out_size; (void)d_ws; (void)ws_size;

  hipFuncSetAttribute((const void*)lstm_spec,
                      hipFuncAttributeMaxDynamicSharedMemorySize, LDS_BYTES);

  lstm_spec<<<B_/R_, NTHR, LDS_BYTES, stream>>>(
      x, w_ih0, w_hh0, b_ih0, b_hh0, w_ih1, w_hh1, b_ih1, b_hh1,
      fc_w, fc_b, (float*)d_out);
}

// Round 6
// 884.789 us; speedup vs baseline: 1.6103x; 1.6103x over previous
//
#include <hip/hip_runtime.h>

// ---- problem constants ----
#define B_   2048
#define T_   512
#define H_   128
#define G_   512
#define R_   8      // batch rows per block
#define NTHR 512    // 8 symmetric waves; wave wv owns units [wv*16, wv*16+16)

typedef _Float16 f16;
typedef _Float16 f16x8 __attribute__((ext_vector_type(8)));
typedef float    f32x4 __attribute__((ext_vector_type(4)));
typedef int      i32x2 __attribute__((ext_vector_type(2)));

// ---- LDS layout (bytes). h tiles: row stride 256 B, XOR swizzle ((row&7)<<4) ----
#define OFF_W1    0                       // w_ih1 f16 [512][128] swizzled = 131072
#define OFF_RING  131072                  // h1 ring: 4 slots x [8][128] f16 = 8192
#define OFF_HB    139264                  // h2 state: 2 bufs x [8][128] f16 = 4096
#define OFF_XT    143360                  // x tiles: 2 bufs x 8 tok x 128 B = 2048
#define LDS_BYTES 145408

__device__ __forceinline__ float rcp_(float v) {
#if __has_builtin(__builtin_amdgcn_rcpf)
  return __builtin_amdgcn_rcpf(v);
#else
  return 1.0f / v;
#endif
}
__device__ __forceinline__ float sig_(float v)  { return rcp_(1.0f + __expf(-v)); }
__device__ __forceinline__ float tanh_(float v) { return 1.0f - 2.0f * rcp_(__expf(2.0f * v) + 1.0f); }

__device__ __forceinline__ f16x8 cvt8(const float* __restrict__ p) {
  float4 a = ((const float4*)p)[0];
  float4 b = ((const float4*)p)[1];
  f16x8 v;
  v[0]=(f16)a.x; v[1]=(f16)a.y; v[2]=(f16)a.z; v[3]=(f16)a.w;
  v[4]=(f16)b.x; v[5]=(f16)b.y; v[6]=(f16)b.z; v[7]=(f16)b.w;
  return v;
}
__device__ __forceinline__ f32x4 mfma16(f16x8 a, f16x8 b, f32x4 c) {
  return __builtin_amdgcn_mfma_f32_16x16x32_f16(a, b, c, 0, 0, 0);
}

// v_permlane32_swap: x = {a.lo, b.lo} (even-row spread), y = {a.hi, b.hi} (odd)
// Validated on HW in round 5 (kernel passed with this path).
__device__ __forceinline__ void pls2_(float a, float b, float& x, float& y) {
#if __has_builtin(__builtin_amdgcn_permlane32_swap)
  i32x2 r = __builtin_amdgcn_permlane32_swap(__float_as_int(a), __float_as_int(b),
                                             false, false);
  x = __int_as_float(r.x); y = __int_as_float(r.y);
#else
  asm volatile("v_permlane32_swap_b32 %0, %1" : "+v"(a), "+v"(b));
  x = a; y = b;
#endif
}

__global__ __launch_bounds__(NTHR, 2)
void lstm_v6(const float* __restrict__ x,
             const float* __restrict__ w_ih0, const float* __restrict__ w_hh0,
             const float* __restrict__ b_ih0, const float* __restrict__ b_hh0,
             const float* __restrict__ w_ih1, const float* __restrict__ w_hh1,
             const float* __restrict__ b_ih1, const float* __restrict__ b_hh1,
             const float* __restrict__ fc_w,  const float* __restrict__ fc_b,
             float* __restrict__ out)
{
  extern __shared__ char lds[];
  char*  w1L   = lds + OFF_W1;
  char*  ringB = lds + OFF_RING;
  char*  hBB   = lds + OFF_HB;
  char*  xT    = lds + OFF_XT;

  const int tid  = (int)threadIdx.x;
  const int lane = tid & 63;
  const int wv   = tid >> 6;
  const int n    = lane & 15;
  const int hi   = lane >> 4;
  const int u0   = wv * 16;
  const int blk  = (int)blockIdx.x;
  const int rsw  = (n & 7) << 4;

  // ---- stage w_ih1 -> LDS f16, swizzled ----
  for (int idx = tid; idx < G_*16; idx += NTHR) {
    const int g = idx >> 4, s7 = idx & 15;
    f16x8 v = cvt8(w_ih1 + g*H_ + s7*8);
    *(f16x8*)(w1L + g*256 + ((s7*16) ^ ((g&7)<<4))) = v;
  }
  // zero ring + hB + xT (14336 B = 3584 dwords); xT pad must stay finite
  for (int i = tid; i < 3584; i += NTHR) ((unsigned*)ringB)[i] = 0u;
  __syncthreads();

  // ---- wave 7: x prologue (chunk 0 -> xT buf0; chunk 1 -> regs) ----
  float xr0 = 0.f, xr1 = 0.f, xr2 = 0.f;
  if (wv == 7) {
    const int tok = lane >> 3, r = lane & 7;
    const size_t base = (size_t)(blk*R_ + r) * T_;
    const float a0 = x[(base + tok)*3+0];
    const float a1 = x[(base + tok)*3+1];
    const float a2 = x[(base + tok)*3+2];
    f16* w = (f16*)(xT + tok*128 + r*16);
    w[0] = (f16)a0; w[1] = (f16)a1; w[2] = (f16)a2;
    xr0 = x[(base + 8 + tok)*3+0];
    xr1 = x[(base + 8 + tok)*3+1];
    xr2 = x[(base + 8 + tok)*3+2];
  }

  // ---- resident weight fragments: 128 VGPRs (proven budget, round 2/4) ----
  f16x8 whh0f[4][4], whh1f[4][4];
  #pragma unroll
  for (int q = 0; q < 4; ++q)
    #pragma unroll
    for (int kc = 0; kc < 4; ++kc) {
      const int off = (q*H_ + u0 + n)*H_ + kc*32 + hi*8;
      whh0f[q][kc] = cvt8(w_hh0 + off);
      whh1f[q][kc] = cvt8(w_hh1 + off);
    }
  // padded w_ih0 B-frags (K=32; k>=3 zero; only hi==0 lanes carry data)
  f16x8 w0p[4];
  float b0[4], bP[4];
  #pragma unroll
  for (int q = 0; q < 4; ++q) {
    const int g = q*H_ + u0 + n;
    b0[q] = b_ih0[g] + b_hh0[g];
    bP[q] = b_ih1[g] + b_hh1[g];
    f16x8 z;
    #pragma unroll
    for (int e = 0; e < 8; ++e) z[e] = (f16)0.f;
    if (hi == 0) {
      z[0] = (f16)w_ih0[g*3+0];
      z[1] = (f16)w_ih0[g*3+1];
      z[2] = (f16)w_ih0[g*3+2];
    }
    w0p[q] = z;
  }

  int offA[4];
  #pragma unroll
  for (int kc = 0; kc < 4; ++kc)
    offA[kc] = (n&7)*256 + ((kc*64 + hi*16) ^ rsw);

  float cA0 = 0.f, cA1 = 0.f, cB0 = 0.f, cB1 = 0.f;
  f32x4 xpP[4];
  const int rowbase = (hi & 1)*4 + ((lane >= 32) ? 2 : 0);
  const int colb    = 2*(u0 + n);
  __syncthreads();

  for (int s = 0; s < T_ + 2; ++s) {
    // ---- x staging: wave 7, once per 8 steps (write c+1 from regs, load c+2) ----
    if (wv == 7 && (s & 7) == 3) {
      const int c = s >> 3;
      const int tok = lane >> 3, r = lane & 7;
      if (c <= 61) {
        const size_t base = (size_t)(blk*R_ + r) * T_ + (8*(c+2) + tok);
        const float a0 = x[base*3+0], a1 = x[base*3+1], a2 = x[base*3+2];
        f16* w = (f16*)(xT + ((c+1)&1)*1024 + tok*128 + r*16);
        w[0] = (f16)xr0; w[1] = (f16)xr1; w[2] = (f16)xr2;
        xr0 = a0; xr1 = a1; xr2 = a2;
      } else if (c == 62) {
        f16* w = (f16*)(xT + ((c+1)&1)*1024 + tok*128 + r*16);
        w[0] = (f16)xr0; w[1] = (f16)xr1; w[2] = (f16)xr2;
      }
    }

    // ---- proj: token pair (s-2 -> rows 0-7, s-1 -> rows 8-15), even steps ----
    if ((s & 1) == 0 && s >= 2 && s <= T_) {
      const char* pa = ringB + ((n < 8) ? (((s-2)&3)*2048) : (((s-1)&3)*2048));
      #pragma unroll
      for (int q = 0; q < 4; ++q)
        { xpP[q][0]=bP[q]; xpP[q][1]=bP[q]; xpP[q][2]=bP[q]; xpP[q][3]=bP[q]; }
      #pragma unroll
      for (int kc = 0; kc < 4; ++kc) {
        const f16x8 a = *(const f16x8*)(pa + offA[kc]);
        #pragma unroll
        for (int q = 0; q < 4; ++q) {
          const f16x8 bf = *(const f16x8*)(w1L + (q*H_ + u0 + n)*256
                                           + ((kc*64 + hi*16) ^ rsw));
          xpP[q] = mfma16(a, bf, xpP[q]);
        }
      }
    }

    // ---- layer 0 (token s) ----
    if (s < T_) {
      const f16x8 ax = *(const f16x8*)(xT + ((s>>3)&1)*1024 + (s&7)*128 + (n&7)*16);
      f32x4 acc[4];
      #pragma unroll
      for (int q = 0; q < 4; ++q) {
        f32x4 a; a[0]=b0[q]; a[1]=b0[q]; a[2]=b0[q]; a[3]=b0[q];
        acc[q] = mfma16(ax, w0p[q], a);
      }
      const char* pa = ringB + ((s-1)&3)*2048;
      #pragma unroll
      for (int kc = 0; kc < 4; ++kc) {
        const f16x8 af = *(const f16x8*)(pa + offA[kc]);
        #pragma unroll
        for (int q = 0; q < 4; ++q) acc[q] = mfma16(af, whh0f[q][kc], acc[q]);
      }
      char* wr = ringB + (s&3)*2048;
      float gA[4], gB[4], d0, d1;
      #pragma unroll
      for (int q = 0; q < 4; ++q) {
        pls2_(acc[q][0], acc[q][2], gA[q], d0);
        pls2_(acc[q][1], acc[q][3], gB[q], d1);
      }
      {
        const float iv = sig_(gA[0]), fv = sig_(gA[1]), gv = tanh_(gA[2]), ov = sig_(gA[3]);
        cA0 = fv*cA0 + iv*gv;
        const float h = ov * tanh_(cA0);
        *(f16*)(wr + rowbase*256 + (colb ^ (rowbase<<4))) = (f16)h;
      }
      {
        const float iv = sig_(gB[0]), fv = sig_(gB[1]), gv = tanh_(gB[2]), ov = sig_(gB[3]);
        cA1 = fv*cA1 + iv*gv;
        const float h = ov * tanh_(cA1);
        *(f16*)(wr + (rowbase+1)*256 + (colb ^ ((rowbase+1)<<4))) = (f16)h;
      }
    }

    // ---- layer 1 (token s-2); odd tokens ride the y-half of the swap ----
    if (s >= 2) {
      const bool odd = (s & 1);
      const char* pb = hBB + (s&1)*2048;
      f32x4 acc[4];
      #pragma unroll
      for (int q = 0; q < 4; ++q) acc[q] = xpP[q];
      #pragma unroll
      for (int kc = 0; kc < 4; ++kc) {
        const f16x8 af = *(const f16x8*)(pb + offA[kc]);
        #pragma unroll
        for (int q = 0; q < 4; ++q) acc[q] = mfma16(af, whh1f[q][kc], acc[q]);
      }
      char* wr = hBB + ((s+1)&1)*2048;
      float gA[4], gB[4];
      #pragma unroll
      for (int q = 0; q < 4; ++q) {
        float ex, ey, fx, fy;
        pls2_(acc[q][0], acc[q][2], ex, ey);
        gA[q] = odd ? ey : ex;
        pls2_(acc[q][1], acc[q][3], fx, fy);
        gB[q] = odd ? fy : fx;
      }
      {
        const float iv = sig_(gA[0]), fv = sig_(gA[1]), gv = tanh_(gA[2]), ov = sig_(gA[3]);
        cB0 = fv*cB0 + iv*gv;
        const float h = ov * tanh_(cB0);
        *(f16*)(wr + rowbase*256 + (colb ^ (rowbase<<4))) = (f16)h;
      }
      {
        const float iv = sig_(gB[0]), fv = sig_(gB[1]), gv = tanh_(gB[2]), ov = sig_(gB[3]);
        cB1 = fv*cB1 + iv*gv;
        const float h = ov * tanh_(cB1);
        *(f16*)(wr + (rowbase+1)*256 + (colb ^ ((rowbase+1)<<4))) = (f16)h;
      }
    }
    __syncthreads();
  }

  // ---- FC head: final h2 in hBB buf (T_+2)&1 == 0 ----
  if (tid < R_*2) {
    const int r = tid >> 1, o = tid & 1;
    float acc = fc_b[o];
    #pragma unroll 4
    for (int d = 0; d < H_; ++d) {
      const f16 hv = *(const f16*)(hBB + r*256 + ((2*d) ^ ((r&7)<<4)));
      acc += (float)hv * fc_w[o*H_ + d];
    }
    out[(blk*R_ + r)*2 + o] = acc;
  }
}

extern "C" void kernel_launch(void* const* d_in, const int* in_sizes, int n_in,
                              void* d_out, int out_size, void* d_ws, size_t ws_size,
                              hipStream_t stream) {
  const float* x     = (const float*)d_in[0];
  const float* w_ih0 = (const float*)d_in[1];
  const float* w_hh0 = (const float*)d_in[2];
  const float* b_ih0 = (const float*)d_in[3];
  const float* b_hh0 = (const float*)d_in[4];
  const float* w_ih1 = (const float*)d_in[5];
  const float* w_hh1 = (const float*)d_in[6];
  const float* b_ih1 = (const float*)d_in[7];
  const float* b_hh1 = (const float*)d_in[8];
  const float* fc_w  = (const float*)d_in[9];
  const float* fc_b  = (const float*)d_in[10];
  (void)in_sizes; (void)n_in; (void)out_size; (void)d_ws; (void)ws_size;

  hipFuncSetAttribute((const void*)lstm_v6,
                      hipFuncAttributeMaxDynamicSharedMemorySize, LDS_BYTES);

  lstm_v6<<<B_/R_, NTHR, LDS_BYTES, stream>>>(
      x, w_ih0, w_hh0, b_ih0, b_hh0, w_ih1, w_hh1, b_ih1, b_hh1,
      fc_w, fc_b, (float*)d_out);
}